// Round 1
// baseline (40260.779 us; speedup 1.0000x reference)
//
#include <hip/hip_runtime.h>

// ---------------------------------------------------------------------------
// VQ-VAE forward, fp32 direct convolutions.
// Layers (B=16):
//  enc: c1a 1->64 s1p2 256   c1b 64->64 s2p0 256->126
//       c2a 64->128 s1p2 126 c2b 128->128 s2p0 126->61
//       c3a 128->64 s1p2 61  c3b 64->64 s2p0 61->29     -> before (B,64,29,29)
//  vq:  idxs (B,29,29), after (B,64,29,29)
//  dec: t3a ct64->128 s2 29->61   t3b ct128->128 s1p2 61
//       t2a ct128->64 s2 61->125  t2b ct64->64 s1p2 125
//       t1a ct64->1 s2 125->253   t1b ct1->1 s1p2 253   -> recon (B,1,253,253)
// ConvT s1p2 == conv s1p2 with flipped+transposed weights (repacked once).
// ConvT s2p0 == conv over 2x-dilated input, pad 4, flipped weights (gather).
// ---------------------------------------------------------------------------

// Direct 5x5 conv + bias + ReLU. Block = 256 threads = 16x16 output tile,
// 8 output channels per block (acc in regs). Input channel slice staged in LDS.
// blockIdx.z = batch image; in/out pointers are image-0 bases.
template<int STRIDE, int PAD>
__global__ __launch_bounds__(256) void conv5x5_relu(
    const float* __restrict__ in, const float* __restrict__ w,  // w: (Co,Ci,5,5)
    const float* __restrict__ bias, float* __restrict__ out,
    int Ci, int Co, int Hin, int Win, int Hout, int Wout, int nTX)
{
    constexpr int IT = (16 - 1) * STRIDE + 5;   // input tile extent (20 or 35)
    __shared__ float s_in[IT * IT];

    const int z = blockIdx.z;
    const float* inz = in + (size_t)z * Ci * Hin * Win;
    float* outz = out + (size_t)z * Co * Hout * Wout;

    const int co0 = blockIdx.y * 8;
    const int ty0 = (blockIdx.x / nTX) * 16;
    const int tx0 = (blockIdx.x % nTX) * 16;
    const int tid = threadIdx.x;
    const int ty = tid >> 4, tx = tid & 15;
    const int oy = ty0 + ty, ox = tx0 + tx;
    const int iy0 = ty0 * STRIDE - PAD;
    const int ix0 = tx0 * STRIDE - PAD;

    float acc[8];
#pragma unroll
    for (int j = 0; j < 8; ++j) acc[j] = 0.f;

    for (int ci = 0; ci < Ci; ++ci) {
        const float* inc = inz + (size_t)ci * Hin * Win;
        for (int i = tid; i < IT * IT; i += 256) {
            int r = i / IT, c = i - r * IT;
            int y = iy0 + r, x = ix0 + c;
            float v = 0.f;
            if (y >= 0 && y < Hin && x >= 0 && x < Win) v = inc[y * Win + x];
            s_in[i] = v;
        }
        __syncthreads();
        const float* wc = w + ((size_t)co0 * Ci + ci) * 25;  // uniform -> s_load
#pragma unroll
        for (int ky = 0; ky < 5; ++ky) {
#pragma unroll
            for (int kx = 0; kx < 5; ++kx) {
                float v = s_in[(ty * STRIDE + ky) * IT + tx * STRIDE + kx];
#pragma unroll
                for (int j = 0; j < 8; ++j) {
                    if (co0 + j < Co)
                        acc[j] += v * wc[(size_t)j * Ci * 25 + ky * 5 + kx];
                }
            }
        }
        __syncthreads();
    }
    if (oy < Hout && ox < Wout) {
#pragma unroll
        for (int j = 0; j < 8; ++j) {
            int co = co0 + j;
            if (co < Co) {
                float r2 = acc[j] + bias[co];
                outz[((size_t)co * Hout + oy) * Wout + ox] = r2 > 0.f ? r2 : 0.f;
            }
        }
    }
}

// ConvTranspose2d stride=2 pad=0 (k=5) as a gather over the dilated input.
// w is repacked (Co,Ci,25), kernel-flipped. Output Hout = 2*Hin + 3.
__global__ __launch_bounds__(256) void convt5x5_s2_relu(
    const float* __restrict__ in, const float* __restrict__ w,
    const float* __restrict__ bias, float* __restrict__ out,
    int Ci, int Co, int Hin, int Win, int Hout, int Wout, int nTX)
{
    constexpr int IT = 12;
    __shared__ float s_in[IT * IT];

    const int z = blockIdx.z;
    const float* inz = in + (size_t)z * Ci * Hin * Win;
    float* outz = out + (size_t)z * Co * Hout * Wout;

    const int co0 = blockIdx.y * 8;
    const int ty0 = (blockIdx.x / nTX) * 16;
    const int tx0 = (blockIdx.x % nTX) * 16;
    const int tid = threadIdx.x;
    const int ty = tid >> 4, tx = tid & 15;
    const int oy = ty0 + ty, ox = tx0 + tx;
    // floor((ty0-4)/2) without negative-division pitfalls
    const int iy0 = (ty0 - 4 + 1024) / 2 - 512;
    const int ix0 = (tx0 - 4 + 1024) / 2 - 512;

    float acc[8];
#pragma unroll
    for (int j = 0; j < 8; ++j) acc[j] = 0.f;

    for (int ci = 0; ci < Ci; ++ci) {
        const float* inc = inz + (size_t)ci * Hin * Win;
        for (int i = tid; i < IT * IT; i += 256) {
            int r = i / IT, c = i - r * IT;
            int y = iy0 + r, x = ix0 + c;
            float v = 0.f;
            if (y >= 0 && y < Hin && x >= 0 && x < Win) v = inc[y * Win + x];
            s_in[i] = v;
        }
        __syncthreads();
        const float* wc = w + ((size_t)co0 * Ci + ci) * 25;
#pragma unroll
        for (int ky = 0; ky < 5; ++ky) {
            int uy = oy - 4 + ky;
            bool vy = (uy >= 0) && ((uy & 1) == 0);
            int rr = (uy >> 1) - iy0;
#pragma unroll
            for (int kx = 0; kx < 5; ++kx) {
                int ux = ox - 4 + kx;
                bool vx = (ux >= 0) && ((ux & 1) == 0);
                int cc = (ux >> 1) - ix0;
                bool ok = vy && vx;
                int idx = ok ? (rr * IT + cc) : 0;   // always in-bounds
                float v = s_in[idx];
                v = ok ? v : 0.f;
#pragma unroll
                for (int j = 0; j < 8; ++j) {
                    if (co0 + j < Co)
                        acc[j] += v * wc[(size_t)j * Ci * 25 + ky * 5 + kx];
                }
            }
        }
        __syncthreads();
    }
    if (oy < Hout && ox < Wout) {
#pragma unroll
        for (int j = 0; j < 8; ++j) {
            int co = co0 + j;
            if (co < Co) {
                float r2 = acc[j] + bias[co];
                outz[((size_t)co * Hout + oy) * Wout + ox] = r2 > 0.f ? r2 : 0.f;
            }
        }
    }
}

// Repack ConvTranspose weight (Ci,Co,5,5) -> (Co,Ci,25) with spatial flip.
__global__ __launch_bounds__(256) void repack_wt(
    const float* __restrict__ src, float* __restrict__ dst, int Ci, int Co)
{
    int n = Ci * Co * 25;
    int i = blockIdx.x * 256 + threadIdx.x;
    if (i >= n) return;
    int t = i % 25;
    int rest = i / 25;
    int ci = rest % Ci;
    int co = rest / Ci;
    dst[i] = src[((size_t)ci * Co + co) * 25 + (24 - t)];
}

// VQ: per position argmin_k( ||e_k||^2 - 2 z.e_k ); write idx (as float) and
// the quantized vector. Codebook e (64,128) staged in LDS.
__global__ __launch_bounds__(256) void vq_kernel(
    const float* __restrict__ before, const float* __restrict__ e,
    float* __restrict__ idxs_out, float* __restrict__ after,
    int npos, int HW)
{
    __shared__ float s_e[64 * 128];
    __shared__ float s_n[128];
    for (int i = threadIdx.x; i < 64 * 128; i += 256) s_e[i] = e[i];
    __syncthreads();
    if (threadIdx.x < 128) {
        int k = threadIdx.x;
        float s = 0.f;
#pragma unroll
        for (int d = 0; d < 64; ++d) { float v = s_e[d * 128 + k]; s += v * v; }
        s_n[k] = s;
    }
    __syncthreads();

    int p = blockIdx.x * 256 + threadIdx.x;
    if (p >= npos) return;
    int b = p / HW, r = p - b * HW;

    float zv[64];
#pragma unroll
    for (int d = 0; d < 64; ++d)
        zv[d] = before[((size_t)b * 64 + d) * HW + r];

    float best = 1e30f;
    int bi = 0;
    for (int k = 0; k < 128; ++k) {
        float dot = 0.f;
#pragma unroll
        for (int d = 0; d < 64; ++d) dot += zv[d] * s_e[d * 128 + k];
        float m = s_n[k] - 2.f * dot;
        if (m < best) { best = m; bi = k; }   // strict <  => first-min, matches argmin
    }
    idxs_out[p] = (float)bi;
#pragma unroll
    for (int d = 0; d < 64; ++d)
        after[((size_t)b * 64 + d) * HW + r] = s_e[d * 128 + bi];
}

extern "C" void kernel_launch(void* const* d_in, const int* in_sizes, int n_in,
                              void* d_out, int out_size, void* d_ws, size_t ws_size,
                              hipStream_t stream)
{
    const float* x     = (const float*)d_in[0];
    const float* e     = (const float*)d_in[1];
    const float* c1a_w = (const float*)d_in[2];  const float* c1a_b = (const float*)d_in[3];
    const float* c1b_w = (const float*)d_in[4];  const float* c1b_b = (const float*)d_in[5];
    const float* c2a_w = (const float*)d_in[6];  const float* c2a_b = (const float*)d_in[7];
    const float* c2b_w = (const float*)d_in[8];  const float* c2b_b = (const float*)d_in[9];
    const float* c3a_w = (const float*)d_in[10]; const float* c3a_b = (const float*)d_in[11];
    const float* c3b_w = (const float*)d_in[12]; const float* c3b_b = (const float*)d_in[13];
    const float* t3a_w = (const float*)d_in[14]; const float* t3a_b = (const float*)d_in[15];
    const float* t3b_w = (const float*)d_in[16]; const float* t3b_b = (const float*)d_in[17];
    const float* t2a_w = (const float*)d_in[18]; const float* t2a_b = (const float*)d_in[19];
    const float* t2b_w = (const float*)d_in[20]; const float* t2b_b = (const float*)d_in[21];
    const float* t1a_w = (const float*)d_in[22]; const float* t1a_b = (const float*)d_in[23];
    const float* t1b_w = (const float*)d_in[24]; const float* t1b_b = (const float*)d_in[25];

    float* out = (float*)d_out;
    float* ws  = (float*)d_ws;

    // workspace layout (floats); regions reused encoder->decoder
    float* h3buf = ws + 0;          // 32,514,048 : h3 (16,128,126,126) / d2 / d4
    float* h2buf = ws + 32514048;   // 16,257,024 : h2 (16,64,126,126)  / d3
    float* h4buf = ws + 48771072;   //  7,618,048 : h4 (16,128,61,61)   / d1
    float* h1buf = ws + 56389120;   //  4,194,304 : h1 per-image (64,256,256) / d5
    float* h5buf = ws + 60583424;   //  3,809,024 : h5 (16,64,61,61)
    float* wfbuf = ws + 64392448;   //    923,225 : repacked ConvT weights
    float* wf_t3a = wfbuf;            // 128*64*25
    float* wf_t3b = wfbuf + 204800;   // 128*128*25
    float* wf_t2a = wfbuf + 614400;   // 64*128*25
    float* wf_t2b = wfbuf + 819200;   // 64*64*25
    float* wf_t1a = wfbuf + 921600;   // 1*64*25
    float* wf_t1b = wfbuf + 923200;   // 25

    if (ws_size < (size_t)(64392448 + 923225) * sizeof(float)) return;  // need ~262 MB

    // d_out layout: recon | idxs | before | after
    float* o_recon  = out;                // 16*1*253*253   = 1,024,144
    float* o_idxs   = out + 1024144;      // 16*29*29       = 13,456
    float* o_before = out + 1037600;      // 16*64*29*29    = 861,184
    float* o_after  = out + 1898784;      // 16*64*29*29    = 861,184

    // --- repack ConvT weights -> conv form ---
    {
        struct { const float* s; float* d; int ci, co; } rp[6] = {
            {t3a_w, wf_t3a, 64, 128}, {t3b_w, wf_t3b, 128, 128},
            {t2a_w, wf_t2a, 128, 64}, {t2b_w, wf_t2b, 64, 64},
            {t1a_w, wf_t1a, 64, 1},   {t1b_w, wf_t1b, 1, 1}};
        for (int i = 0; i < 6; ++i) {
            int n = rp[i].ci * rp[i].co * 25;
            repack_wt<<<dim3((n + 255) / 256), 256, 0, stream>>>(rp[i].s, rp[i].d, rp[i].ci, rp[i].co);
        }
    }

    // --- encoder ---
    // first two layers per-image so the 268 MB h1 tensor never materializes
    for (int b = 0; b < 16; ++b) {
        conv5x5_relu<1, 2><<<dim3(16 * 16, 8, 1), 256, 0, stream>>>(
            x + (size_t)b * 256 * 256, c1a_w, c1a_b, h1buf,
            1, 64, 256, 256, 256, 256, 16);
        conv5x5_relu<2, 0><<<dim3(8 * 8, 8, 1), 256, 0, stream>>>(
            h1buf, c1b_w, c1b_b, h2buf + (size_t)b * 64 * 126 * 126,
            64, 64, 256, 256, 126, 126, 8);
    }
    conv5x5_relu<1, 2><<<dim3(8 * 8, 16, 16), 256, 0, stream>>>(
        h2buf, c2a_w, c2a_b, h3buf, 64, 128, 126, 126, 126, 126, 8);
    conv5x5_relu<2, 0><<<dim3(4 * 4, 16, 16), 256, 0, stream>>>(
        h3buf, c2b_w, c2b_b, h4buf, 128, 128, 126, 126, 61, 61, 4);
    conv5x5_relu<1, 2><<<dim3(4 * 4, 8, 16), 256, 0, stream>>>(
        h4buf, c3a_w, c3a_b, h5buf, 128, 64, 61, 61, 61, 61, 4);
    conv5x5_relu<2, 0><<<dim3(2 * 2, 8, 16), 256, 0, stream>>>(
        h5buf, c3b_w, c3b_b, o_before, 64, 64, 61, 61, 29, 29, 2);

    // --- VQ ---
    vq_kernel<<<dim3(53), 256, 0, stream>>>(o_before, e, o_idxs, o_after, 13456, 841);

    // --- decoder ---
    convt5x5_s2_relu<<<dim3(4 * 4, 16, 16), 256, 0, stream>>>(
        o_after, wf_t3a, t3a_b, h4buf, 64, 128, 29, 29, 61, 61, 4);          // d1
    conv5x5_relu<1, 2><<<dim3(4 * 4, 16, 16), 256, 0, stream>>>(
        h4buf, wf_t3b, t3b_b, h3buf, 128, 128, 61, 61, 61, 61, 4);           // d2
    convt5x5_s2_relu<<<dim3(8 * 8, 8, 16), 256, 0, stream>>>(
        h3buf, wf_t2a, t2a_b, h2buf, 128, 64, 61, 61, 125, 125, 8);          // d3
    conv5x5_relu<1, 2><<<dim3(8 * 8, 8, 16), 256, 0, stream>>>(
        h2buf, wf_t2b, t2b_b, h3buf, 64, 64, 125, 125, 125, 125, 8);         // d4
    convt5x5_s2_relu<<<dim3(16 * 16, 1, 16), 256, 0, stream>>>(
        h3buf, wf_t1a, t1a_b, h1buf, 64, 1, 125, 125, 253, 253, 16);         // d5
    conv5x5_relu<1, 2><<<dim3(16 * 16, 1, 16), 256, 0, stream>>>(
        h1buf, wf_t1b, t1b_b, o_recon, 1, 1, 253, 253, 253, 253, 16);        // recon
}

// Round 3
// 7180.849 us; speedup vs baseline: 5.6067x; 5.6067x over previous
//
#include <hip/hip_runtime.h>

// ---------------------------------------------------------------------------
// VQ-VAE forward, fp32, register-blocked direct convolutions.
//  enc: c1a 1->64 s1p2 256   c1b 64->64 s2p0 256->126
//       c2a 64->128 s1p2 126 c2b 128->128 s2p0 126->61
//       c3a 128->64 s1p2 61  c3b 64->64 s2p0 61->29     -> before (B,64,29,29)
//  vq:  idxs (B,29,29), after (B,64,29,29)
//  dec: t3a ct64->128 s2 29->61   t3b ct128->128 s1p2 61
//       t2a ct128->64 s2 61->125  t2b ct64->64 s1p2 125
//       t1a ct64->1 s2 125->253   t1b ct1->1 s1p2 253   -> recon (B,1,253,253)
// ConvT s1p2 == conv s1p2 with flipped+transposed weights (repacked once).
// ConvT s2p0 == per-parity 2x2 "quad" gather (exact tap decomposition).
// Round-3 fix: workspace sizes for 61x61 tensors were wrong (7,618,048 vs the
// true 16*128*61*61 = 7,620,608) causing h4/h5 and r1/r2 overlap races. All
// plan offsets are now constexpr-derived; kernels unchanged.
// ---------------------------------------------------------------------------

// ---- stride-1 5x5 conv + bias + ReLU -------------------------------------
// 256 thr = 32 rows x 8 col-quads; thread: 4 consecutive x-pixels x CO_PER co.
// LDS: 2 input channels of 36x36 tile per barrier round. float4 windows.
template<int CO_PER>
__global__ __launch_bounds__(256) void conv5x5_s1(
    const float* __restrict__ in, const float* __restrict__ w,   // w (Co,Ci,25)
    const float* __restrict__ bias, float* __restrict__ out,
    int Ci, int Co, int Hin, int Win, int Hout, int Wout, int nTX)
{
    __shared__ float s_in[2][36 * 36];
    const int z = blockIdx.z;
    const float* inz = in + (size_t)z * Ci * Hin * Win;
    float* outz = out + (size_t)z * Co * Hout * Wout;
    const int co0 = blockIdx.y * CO_PER;
    const int ty0 = ((int)blockIdx.x / nTX) * 32;
    const int tx0 = ((int)blockIdx.x % nTX) * 32;
    const int tid = threadIdx.x;
    const int r  = tid >> 3;
    const int c4 = (tid & 7) * 4;
    const int oy = ty0 + r;
    const int ox0 = tx0 + c4;
    const int iy0 = ty0 - 2, ix0 = tx0 - 2;

    float acc[CO_PER][4];
#pragma unroll
    for (int j = 0; j < CO_PER; ++j)
#pragma unroll
        for (int p = 0; p < 4; ++p) acc[j][p] = 0.f;

    for (int ci0 = 0; ci0 < Ci; ci0 += 2) {
        const int nci = (Ci - ci0 >= 2) ? 2 : 1;
        for (int s = 0; s < nci; ++s) {
            const float* inc = inz + (size_t)(ci0 + s) * Hin * Win;
            for (int i = tid; i < 36 * 36; i += 256) {
                int rr = i / 36, cc = i - rr * 36;
                int y = iy0 + rr, x = ix0 + cc;
                float v = 0.f;
                if (y >= 0 && y < Hin && x >= 0 && x < Win) v = inc[y * Win + x];
                s_in[s][i] = v;
            }
        }
        __syncthreads();
        for (int s = 0; s < nci; ++s) {
            const float* wc = w + (co0 * Ci + ci0 + s) * 25;
            float win[5][8];
#pragma unroll
            for (int ky = 0; ky < 5; ++ky) {
                const float* rowp = &s_in[s][(r + ky) * 36 + c4];
                float4 a = *(const float4*)rowp;
                float4 b = *(const float4*)(rowp + 4);
                win[ky][0]=a.x; win[ky][1]=a.y; win[ky][2]=a.z; win[ky][3]=a.w;
                win[ky][4]=b.x; win[ky][5]=b.y; win[ky][6]=b.z; win[ky][7]=b.w;
            }
#pragma unroll
            for (int j = 0; j < CO_PER; ++j) {
#pragma unroll
                for (int ky = 0; ky < 5; ++ky) {
#pragma unroll
                    for (int kx = 0; kx < 5; ++kx) {
                        float wv = wc[j * Ci * 25 + ky * 5 + kx];
#pragma unroll
                        for (int p = 0; p < 4; ++p)
                            acc[j][p] = fmaf(win[ky][p + kx], wv, acc[j][p]);
                    }
                }
            }
        }
        __syncthreads();
    }
    if (oy < Hout) {
#pragma unroll
        for (int j = 0; j < CO_PER; ++j) {
            const int co = co0 + j;
            const float bv = bias[co];
            float* orow = outz + (size_t)co * Hout * Wout + (size_t)oy * Wout;
#pragma unroll
            for (int p = 0; p < 4; ++p) {
                int ox = ox0 + p;
                if (ox < Wout) {
                    float v = acc[j][p] + bv;
                    orow[ox] = v > 0.f ? v : 0.f;
                }
            }
        }
    }
}

// ---- stride-2 5x5 conv + bias + ReLU -------------------------------------
// 256 thr = 2 co-halves x 16 rows x 8 col-quads; thread: 4 x-pixels x 8 co.
// Block output: 16 rows x 32 cols x 16 co. LDS: 2 ci of 35x67 tile (stride 76).
__global__ __launch_bounds__(256) void conv5x5_s2(
    const float* __restrict__ in, const float* __restrict__ w,
    const float* __restrict__ bias, float* __restrict__ out,
    int Ci, int Co, int Hin, int Win, int Hout, int Wout, int nTX)
{
    __shared__ float s_in[2][35 * 76];
    const int z = blockIdx.z;
    const float* inz = in + (size_t)z * Ci * Hin * Win;
    float* outz = out + (size_t)z * Co * Hout * Wout;
    const int tid = threadIdx.x;
    const int cq = tid & 7;
    const int r  = (tid >> 3) & 15;
    const int g  = tid >> 7;
    const int co0 = blockIdx.y * 16 + g * 8;
    const int ty0 = ((int)blockIdx.x / nTX) * 16;
    const int tx0 = ((int)blockIdx.x % nTX) * 32;
    const int oy = ty0 + r;
    const int ox0 = tx0 + cq * 4;
    const int iy0 = ty0 * 2, ix0 = tx0 * 2;

    float acc[8][4];
#pragma unroll
    for (int j = 0; j < 8; ++j)
#pragma unroll
        for (int p = 0; p < 4; ++p) acc[j][p] = 0.f;

    for (int ci0 = 0; ci0 < Ci; ci0 += 2) {
        const int nci = (Ci - ci0 >= 2) ? 2 : 1;
        for (int s = 0; s < nci; ++s) {
            const float* inc = inz + (size_t)(ci0 + s) * Hin * Win;
            for (int i = tid; i < 35 * 67; i += 256) {
                int rr = i / 67, cc = i - rr * 67;
                int y = iy0 + rr, x = ix0 + cc;
                float v = 0.f;
                if (y >= 0 && y < Hin && x >= 0 && x < Win) v = inc[y * Win + x];
                s_in[s][rr * 76 + cc] = v;
            }
        }
        __syncthreads();
        for (int s = 0; s < nci; ++s) {
            const float* wc = w + (co0 * Ci + ci0 + s) * 25;
            float win[5][12];
#pragma unroll
            for (int ky = 0; ky < 5; ++ky) {
                const float* rowp = &s_in[s][(2 * r + ky) * 76 + cq * 8];
                float4 a = *(const float4*)rowp;
                float4 b = *(const float4*)(rowp + 4);
                float4 c = *(const float4*)(rowp + 8);
                win[ky][0]=a.x; win[ky][1]=a.y; win[ky][2]=a.z;  win[ky][3]=a.w;
                win[ky][4]=b.x; win[ky][5]=b.y; win[ky][6]=b.z;  win[ky][7]=b.w;
                win[ky][8]=c.x; win[ky][9]=c.y; win[ky][10]=c.z; win[ky][11]=c.w;
            }
#pragma unroll
            for (int j = 0; j < 8; ++j) {
#pragma unroll
                for (int ky = 0; ky < 5; ++ky) {
#pragma unroll
                    for (int kx = 0; kx < 5; ++kx) {
                        float wv = wc[j * Ci * 25 + ky * 5 + kx];
#pragma unroll
                        for (int p = 0; p < 4; ++p)
                            acc[j][p] = fmaf(win[ky][2 * p + kx], wv, acc[j][p]);
                    }
                }
            }
        }
        __syncthreads();
    }
    if (oy < Hout) {
#pragma unroll
        for (int j = 0; j < 8; ++j) {
            const int co = co0 + j;
            const float bv = bias[co];
            float* orow = outz + (size_t)co * Hout * Wout + (size_t)oy * Wout;
#pragma unroll
            for (int p = 0; p < 4; ++p) {
                int ox = ox0 + p;
                if (ox < Wout) {
                    float v = acc[j][p] + bv;
                    orow[ox] = v > 0.f ? v : 0.f;
                }
            }
        }
    }
}

// ---- ConvTranspose2d stride=2 pad=0 (k=5): exact 2x2-phase quad gather ----
// out(2a+sy, 2b+sx) uses flipped-kernel taps t=2ty+sy on input rows a-2+ty.
// 256 thr = 16x16 quads, CO_PER co each.
template<int CO_PER>
__global__ __launch_bounds__(256) void convt5x5_quad(
    const float* __restrict__ in, const float* __restrict__ w,  // flipped (Co,Ci,25)
    const float* __restrict__ bias, float* __restrict__ out,
    int Ci, int Co, int Hin, int Win, int Hout, int Wout, int nTX)
{
    __shared__ float s_in[2][18 * 20];
    const int z = blockIdx.z;
    const float* inz = in + (size_t)z * Ci * Hin * Win;
    float* outz = out + (size_t)z * Co * Hout * Wout;
    const int co0 = blockIdx.y * CO_PER;
    const int a0 = ((int)blockIdx.x / nTX) * 16;
    const int b0 = ((int)blockIdx.x % nTX) * 16;
    const int tid = threadIdx.x;
    const int r = tid >> 4, c = tid & 15;

    float acc[CO_PER][4];
#pragma unroll
    for (int j = 0; j < CO_PER; ++j)
#pragma unroll
        for (int p = 0; p < 4; ++p) acc[j][p] = 0.f;

    for (int ci0 = 0; ci0 < Ci; ci0 += 2) {
        const int nci = (Ci - ci0 >= 2) ? 2 : 1;
        for (int s = 0; s < nci; ++s) {
            const float* inc = inz + (size_t)(ci0 + s) * Hin * Win;
            for (int i = tid; i < 18 * 18; i += 256) {
                int rr = i / 18, cc = i - rr * 18;
                int y = a0 - 2 + rr, x = b0 - 2 + cc;
                float v = 0.f;
                if (y >= 0 && y < Hin && x >= 0 && x < Win) v = inc[y * Win + x];
                s_in[s][rr * 20 + cc] = v;
            }
        }
        __syncthreads();
        for (int s = 0; s < nci; ++s) {
            const float* wc = w + (co0 * Ci + ci0 + s) * 25;
            float v[3][3];
#pragma unroll
            for (int i = 0; i < 3; ++i)
#pragma unroll
                for (int jx = 0; jx < 3; ++jx)
                    v[i][jx] = s_in[s][(r + i) * 20 + c + jx];
#pragma unroll
            for (int j = 0; j < CO_PER; ++j) {
                const float* wj = wc + j * Ci * 25;
#pragma unroll
                for (int ty = 0; ty < 3; ++ty)
#pragma unroll
                    for (int tx = 0; tx < 3; ++tx)
                        acc[j][0] = fmaf(v[ty][tx], wj[2*ty*5 + 2*tx], acc[j][0]);
#pragma unroll
                for (int ty = 0; ty < 3; ++ty)
#pragma unroll
                    for (int tx = 0; tx < 2; ++tx)
                        acc[j][1] = fmaf(v[ty][tx+1], wj[2*ty*5 + 2*tx+1], acc[j][1]);
#pragma unroll
                for (int ty = 0; ty < 2; ++ty)
#pragma unroll
                    for (int tx = 0; tx < 3; ++tx)
                        acc[j][2] = fmaf(v[ty+1][tx], wj[(2*ty+1)*5 + 2*tx], acc[j][2]);
#pragma unroll
                for (int ty = 0; ty < 2; ++ty)
#pragma unroll
                    for (int tx = 0; tx < 2; ++tx)
                        acc[j][3] = fmaf(v[ty+1][tx+1], wj[(2*ty+1)*5 + 2*tx+1], acc[j][3]);
            }
        }
        __syncthreads();
    }
    const int a = a0 + r, bq = b0 + c;
#pragma unroll
    for (int j = 0; j < CO_PER; ++j) {
        const int co = co0 + j;
        const float bv = bias[co];
        float* oc = outz + (size_t)co * Hout * Wout;
#pragma unroll
        for (int sy = 0; sy < 2; ++sy) {
            int oy = 2 * a + sy;
            if (oy < Hout) {
#pragma unroll
                for (int sx = 0; sx < 2; ++sx) {
                    int ox = 2 * bq + sx;
                    if (ox < Wout) {
                        float vv = acc[j][sy * 2 + sx] + bv;
                        oc[(size_t)oy * Wout + ox] = vv > 0.f ? vv : 0.f;
                    }
                }
            }
        }
    }
}

// Repack ConvTranspose weight (Ci,Co,5,5) -> (Co,Ci,25) with spatial flip.
__global__ __launch_bounds__(256) void repack_wt(
    const float* __restrict__ src, float* __restrict__ dst, int Ci, int Co)
{
    int n = Ci * Co * 25;
    int i = blockIdx.x * 256 + threadIdx.x;
    if (i >= n) return;
    int t = i % 25;
    int rest = i / 25;
    int ci = rest % Ci;
    int co = rest / Ci;
    dst[i] = src[((size_t)ci * Co + co) * 25 + (24 - t)];
}

// VQ: per position argmin_k( ||e_k||^2 - 2 z.e_k ); strict < == first-min.
__global__ __launch_bounds__(256) void vq_kernel(
    const float* __restrict__ before, const float* __restrict__ e,
    float* __restrict__ idxs_out, float* __restrict__ after,
    int npos, int HW)
{
    __shared__ float s_e[64 * 128];
    __shared__ float s_n[128];
    for (int i = threadIdx.x; i < 64 * 128; i += 256) s_e[i] = e[i];
    __syncthreads();
    if (threadIdx.x < 128) {
        int k = threadIdx.x;
        float s = 0.f;
#pragma unroll
        for (int d = 0; d < 64; ++d) { float v = s_e[d * 128 + k]; s += v * v; }
        s_n[k] = s;
    }
    __syncthreads();

    int p = blockIdx.x * 256 + threadIdx.x;
    if (p >= npos) return;
    int b = p / HW, r = p - b * HW;

    float zv[64];
#pragma unroll
    for (int d = 0; d < 64; ++d)
        zv[d] = before[((size_t)b * 64 + d) * HW + r];

    float best = 1e30f;
    int bi = 0;
    for (int k = 0; k < 128; ++k) {
        float dot = 0.f;
#pragma unroll
        for (int d = 0; d < 64; ++d) dot += zv[d] * s_e[d * 128 + k];
        float m = s_n[k] - 2.f * dot;
        if (m < best) { best = m; bi = k; }
    }
    idxs_out[p] = (float)bi;
#pragma unroll
    for (int d = 0; d < 64; ++d)
        after[((size_t)b * 64 + d) * HW + r] = s_e[d * 128 + bi];
}

extern "C" void kernel_launch(void* const* d_in, const int* in_sizes, int n_in,
                              void* d_out, int out_size, void* d_ws, size_t ws_size,
                              hipStream_t stream)
{
    const float* x     = (const float*)d_in[0];
    const float* e     = (const float*)d_in[1];
    const float* c1a_w = (const float*)d_in[2];  const float* c1a_b = (const float*)d_in[3];
    const float* c1b_w = (const float*)d_in[4];  const float* c1b_b = (const float*)d_in[5];
    const float* c2a_w = (const float*)d_in[6];  const float* c2a_b = (const float*)d_in[7];
    const float* c2b_w = (const float*)d_in[8];  const float* c2b_b = (const float*)d_in[9];
    const float* c3a_w = (const float*)d_in[10]; const float* c3a_b = (const float*)d_in[11];
    const float* c3b_w = (const float*)d_in[12]; const float* c3b_b = (const float*)d_in[13];
    const float* t3a_w = (const float*)d_in[14]; const float* t3a_b = (const float*)d_in[15];
    const float* t3b_w = (const float*)d_in[16]; const float* t3b_b = (const float*)d_in[17];
    const float* t2a_w = (const float*)d_in[18]; const float* t2a_b = (const float*)d_in[19];
    const float* t2b_w = (const float*)d_in[20]; const float* t2b_b = (const float*)d_in[21];
    const float* t1a_w = (const float*)d_in[22]; const float* t1a_b = (const float*)d_in[23];
    const float* t1b_w = (const float*)d_in[24]; const float* t1b_b = (const float*)d_in[25];

    float* out = (float*)d_out;
    float* ws  = (float*)d_ws;

    // d_out layout: recon | idxs | before | after
    float* o_recon  = out;                // 16*253*253 = 1,024,144
    float* o_idxs   = out + 1024144;     // 16*29*29   = 13,456
    float* o_before = out + 1037600;     // 16*64*29*29= 861,184
    float* o_after  = out + 1898784;     // 861,184

    // --- exact tensor sizes (floats), constexpr so they can't drift ---
    constexpr size_t S_H1F  = (size_t)16 * 64 * 256 * 256;   // 67,108,864
    constexpr size_t S_H1G  = (size_t)8  * 64 * 256 * 256;   // 33,554,432
    constexpr size_t S126x64  = (size_t)16 * 64  * 126 * 126; // 16,257,024
    constexpr size_t S126x128 = (size_t)16 * 128 * 126 * 126; // 32,514,048
    constexpr size_t S61x128  = (size_t)16 * 128 * 61 * 61;   // 7,620,608
    constexpr size_t S61x64   = (size_t)16 * 64  * 61 * 61;   // 3,810,304
    constexpr size_t S125x64  = (size_t)16 * 64  * 125 * 125; // 16,000,000
    constexpr size_t S253     = (size_t)16 * 253 * 253;       // 1,024,144
    constexpr size_t S_WF     = 923232;  // repacked ConvT weights (padded to /4)

    // ---- full-batch plan ----
    constexpr size_t F_h1 = 0;
    constexpr size_t F_h2 = F_h1 + S_H1F;            // 67,108,864
    constexpr size_t F_h3 = 0;                       // aliases dead h1
    constexpr size_t F_h4 = F_h3 + S126x128;         // 32,514,048
    constexpr size_t F_h5 = F_h4 + S61x128;          // 40,134,656
    constexpr size_t F_wf = F_h5 + S61x64;           // 43,944,960
    constexpr size_t F_r1 = F_wf + S_WF;             // 44,868,192
    constexpr size_t F_r2 = F_r1 + S61x128;          // 52,488,800
    constexpr size_t F_r3 = 0;                       // aliases dead h3/h4
    constexpr size_t F_r4 = F_r3 + S125x64;          // 16,000,000
    constexpr size_t F_r5 = F_r2 + S61x128;          // 60,109,408
    constexpr size_t FULL_NEED = F_h2 + S126x64;     // 83,365,888 (max extent)

    // ---- 8-image-group fallback plan ----
    constexpr size_t G_h1 = 0;
    constexpr size_t G_h2 = G_h1 + S_H1G;            // 33,554,432
    constexpr size_t G_h3 = 0;
    constexpr size_t G_h4 = G_h2;                    // aliases dead h2? NO: h2 live!
    // NOTE: in fallback, c2a reads h2 and writes h3=[0,32.5M); c2b reads h3 and
    // may overwrite h2 (dead after c2a). h4 placed at h2's start:
    constexpr size_t G_h5 = G_h4 + S61x128;          // 41,175,040
    constexpr size_t G_wf = G_h2 + S126x64;          // 49,811,456 (after h2 end)
    constexpr size_t G_r1 = 0;
    constexpr size_t G_r2 = G_r1 + S61x128;          // 7,620,608
    constexpr size_t G_r3 = G_r2 + S61x128;          // 15,241,216
    constexpr size_t G_r4 = G_r3 + S125x64;          // 31,241,216
    constexpr size_t G_r5 = G_r4 + S125x64;          // 47,241,216 (+S253 < G_wf)
    constexpr size_t G8_NEED = G_wf + S_WF;          // 50,734,688

    static_assert(F_h5 + S61x64 <= F_wf, "h5/wf");
    static_assert(F_r5 + S253 <= FULL_NEED, "r5 fits");
    static_assert(G_r5 + S253 <= G_wf, "g8 r5/wf");
    static_assert(G_h5 + S61x64 <= G_wf, "g8 h5/wf");

    if (ws_size < G8_NEED * sizeof(float)) return;
    const bool full = ws_size >= FULL_NEED * sizeof(float);

    float *h1, *h2, *h3, *h4, *h5, *wf, *r1, *r2, *r3, *r4, *r5;
    if (full) {
        h1 = ws + F_h1; h2 = ws + F_h2; h3 = ws + F_h3; h4 = ws + F_h4;
        h5 = ws + F_h5; wf = ws + F_wf; r1 = ws + F_r1; r2 = ws + F_r2;
        r3 = ws + F_r3; r4 = ws + F_r4; r5 = ws + F_r5;
    } else {
        h1 = ws + G_h1; h2 = ws + G_h2; h3 = ws + G_h3; h4 = ws + G_h4;
        h5 = ws + G_h5; wf = ws + G_wf; r1 = ws + G_r1; r2 = ws + G_r2;
        r3 = ws + G_r3; r4 = ws + G_r4; r5 = ws + G_r5;
    }
    float* wf_t3a = wf;              // 128*64*25  = 204,800
    float* wf_t3b = wf + 204800;     // 128*128*25 = 409,600
    float* wf_t2a = wf + 614400;     // 64*128*25  = 204,800
    float* wf_t2b = wf + 819200;     // 64*64*25   = 102,400
    float* wf_t1a = wf + 921600;     // 1*64*25    =   1,600
    float* wf_t1b = wf + 923200;     // 25

    // --- encoder ---
    if (full) {
        conv5x5_s1<8><<<dim3(64, 8, 16), 256, 0, stream>>>(
            x, c1a_w, c1a_b, h1, 1, 64, 256, 256, 256, 256, 8);
        conv5x5_s2<<<dim3(32, 4, 16), 256, 0, stream>>>(
            h1, c1b_w, c1b_b, h2, 64, 64, 256, 256, 126, 126, 4);
    } else {
        for (int g = 0; g < 2; ++g) {
            conv5x5_s1<8><<<dim3(64, 8, 8), 256, 0, stream>>>(
                x + (size_t)g * 8 * 65536, c1a_w, c1a_b, h1,
                1, 64, 256, 256, 256, 256, 8);
            conv5x5_s2<<<dim3(32, 4, 8), 256, 0, stream>>>(
                h1, c1b_w, c1b_b, h2 + (size_t)g * 8 * 64 * 126 * 126,
                64, 64, 256, 256, 126, 126, 4);
        }
    }
    conv5x5_s1<8><<<dim3(16, 16, 16), 256, 0, stream>>>(
        h2, c2a_w, c2a_b, h3, 64, 128, 126, 126, 126, 126, 4);
    conv5x5_s2<<<dim3(8, 8, 16), 256, 0, stream>>>(
        h3, c2b_w, c2b_b, h4, 128, 128, 126, 126, 61, 61, 2);
    conv5x5_s1<8><<<dim3(4, 8, 16), 256, 0, stream>>>(
        h4, c3a_w, c3a_b, h5, 128, 64, 61, 61, 61, 61, 2);
    conv5x5_s2<<<dim3(2, 4, 16), 256, 0, stream>>>(
        h5, c3b_w, c3b_b, o_before, 64, 64, 61, 61, 29, 29, 1);

    // --- VQ ---
    vq_kernel<<<dim3(53), 256, 0, stream>>>(o_before, e, o_idxs, o_after, 13456, 841);

    // --- repack ConvT weights (wf region is dead scratch by now) ---
    {
        struct { const float* s; float* d; int ci, co; } rp[6] = {
            {t3a_w, wf_t3a, 64, 128}, {t3b_w, wf_t3b, 128, 128},
            {t2a_w, wf_t2a, 128, 64}, {t2b_w, wf_t2b, 64, 64},
            {t1a_w, wf_t1a, 64, 1},   {t1b_w, wf_t1b, 1, 1}};
        for (int i = 0; i < 6; ++i) {
            int n = rp[i].ci * rp[i].co * 25;
            repack_wt<<<dim3((n + 255) / 256), 256, 0, stream>>>(
                rp[i].s, rp[i].d, rp[i].ci, rp[i].co);
        }
    }

    // --- decoder ---
    convt5x5_quad<8><<<dim3(4, 16, 16), 256, 0, stream>>>(
        o_after, wf_t3a, t3a_b, r1, 64, 128, 29, 29, 61, 61, 2);      // d1
    conv5x5_s1<8><<<dim3(4, 16, 16), 256, 0, stream>>>(
        r1, wf_t3b, t3b_b, r2, 128, 128, 61, 61, 61, 61, 2);          // d2
    convt5x5_quad<8><<<dim3(16, 8, 16), 256, 0, stream>>>(
        r2, wf_t2a, t2a_b, r3, 128, 64, 61, 61, 125, 125, 4);         // d3
    conv5x5_s1<8><<<dim3(16, 8, 16), 256, 0, stream>>>(
        r3, wf_t2b, t2b_b, r4, 64, 64, 125, 125, 125, 125, 4);        // d4
    convt5x5_quad<1><<<dim3(64, 1, 16), 256, 0, stream>>>(
        r4, wf_t1a, t1a_b, r5, 64, 1, 125, 125, 253, 253, 8);         // d5
    conv5x5_s1<1><<<dim3(64, 1, 16), 256, 0, stream>>>(
        r5, wf_t1b, t1b_b, o_recon, 1, 1, 253, 253, 253, 253, 8);     // recon
}

// Round 4
// 5756.323 us; speedup vs baseline: 6.9942x; 1.2475x over previous
//
#include <hip/hip_runtime.h>

// ---------------------------------------------------------------------------
// VQ-VAE forward. Encoder + VQ + t1a/t1b: fp32 vector (argmin-exact, passing).
// Decoder heavy layers (t3a,t3b,t2a,t2b): bf16 MFMA 16x16x32 with hi/lo split
// (3 products: AhBh+AhBl+AlBh, rel err ~1e-5).
//  enc: c1a 1->64 s1p2 256   c1b 64->64 s2p0 256->126
//       c2a 64->128 s1p2 126 c2b 128->128 s2p0 126->61
//       c3a 128->64 s1p2 61  c3b 64->64 s2p0 61->29     -> before (B,64,29,29)
//  vq:  idxs (B,29,29), after (B,64,29,29)
//  dec: t3a ct64->128 s2 29->61   t3b ct128->128 s1p2 61
//       t2a ct128->64 s2 61->125  t2b ct64->64 s1p2 125
//       t1a ct64->1 s2 125->253   t1b ct1->1 s1p2 253   -> recon (B,1,253,253)
// ConvT s1p2 == conv s1p2 with flipped+transposed weights.
// ConvT s2p0 == 4 exact parity sub-convs (tap tables below == verified quad).
// ---------------------------------------------------------------------------

using f32x4 = __attribute__((ext_vector_type(4))) float;
using bfrag = __attribute__((ext_vector_type(8))) short;   // 8 x bf16

// tap tables: mode 0 = 25-tap s1 conv; modes 1..4 = convT-s2 parities
// (sy,sx) = (0,0),(0,1),(1,0),(1,1). dy/dx are input offsets; wi indexes the
// FLIPPED (Co,Ci,25) weight == src[ci][co][24-wi].
constexpr int MT_N[5] = {25, 9, 6, 6, 4};
constexpr int MT_DY[5][25] = {
  {-2,-2,-2,-2,-2,-1,-1,-1,-1,-1,0,0,0,0,0,1,1,1,1,1,2,2,2,2,2},
  {-2,-2,-2,-1,-1,-1, 0, 0, 0, 0,0,0,0,0,0,0,0,0,0,0,0,0,0,0,0},
  {-2,-2,-1,-1, 0, 0, 0, 0, 0, 0,0,0,0,0,0,0,0,0,0,0,0,0,0,0,0},
  {-1,-1,-1, 0, 0, 0, 0, 0, 0, 0,0,0,0,0,0,0,0,0,0,0,0,0,0,0,0},
  {-1,-1, 0, 0, 0, 0, 0, 0, 0, 0,0,0,0,0,0,0,0,0,0,0,0,0,0,0,0}};
constexpr int MT_DX[5][25] = {
  {-2,-1,0,1,2,-2,-1,0,1,2,-2,-1,0,1,2,-2,-1,0,1,2,-2,-1,0,1,2},
  {-2,-1, 0,-2,-1, 0,-2,-1, 0, 0,0,0,0,0,0,0,0,0,0,0,0,0,0,0,0},
  {-1, 0,-1, 0,-1, 0, 0, 0, 0, 0,0,0,0,0,0,0,0,0,0,0,0,0,0,0,0},
  {-2,-1, 0,-2,-1, 0, 0, 0, 0, 0,0,0,0,0,0,0,0,0,0,0,0,0,0,0,0},
  {-1, 0,-1, 0, 0, 0, 0, 0, 0, 0,0,0,0,0,0,0,0,0,0,0,0,0,0,0,0}};
constexpr int MT_WI[5][25] = {
  {0,1,2,3,4,5,6,7,8,9,10,11,12,13,14,15,16,17,18,19,20,21,22,23,24},
  {0, 2, 4,10,12,14,20,22,24, 0,0,0,0,0,0,0,0,0,0,0,0,0,0,0,0},
  {1, 3,11,13,21,23, 0, 0, 0, 0,0,0,0,0,0,0,0,0,0,0,0,0,0,0,0},
  {5, 7, 9,15,17,19, 0, 0, 0, 0,0,0,0,0,0,0,0,0,0,0,0,0,0,0,0},
  {6, 8,16,18, 0, 0, 0, 0, 0, 0,0,0,0,0,0,0,0,0,0,0,0,0,0,0,0}};

__device__ __forceinline__ unsigned short bf16rne(float f) {
    unsigned u = __float_as_uint(f);
    return (unsigned short)((u + 0x7fffu + ((u >> 16) & 1u)) >> 16);
}

// ---- MFMA weight pack: src (Ci,Co,5,5) convT weight -> per-tap fragments ---
// dst layout: [t][cb][cof][hl][lane][j] ushort bf16; co=cof*16+(lane&15),
// ci=cb*32+(lane>>4)*8+j; value = flipped wf[co][ci][wi] = src[ci][co][24-wi].
template<int MODE>
__global__ __launch_bounds__(256) void pack_w_mfma(
    const float* __restrict__ src, unsigned short* __restrict__ dst,
    int Ci, int Co)
{
    constexpr int NT = MT_N[MODE];
    const int nCB = Ci >> 5, nCoF = Co >> 4;
    const int total = NT * nCB * nCoF * 512;
    int idx = blockIdx.x * 256 + threadIdx.x;
    if (idx >= total) return;
    int j = idx & 7, lane = (idx >> 3) & 63;
    int rest = idx >> 9;
    int cof = rest % nCoF; int rest2 = rest / nCoF;
    int cb = rest2 % nCB;  int t = rest2 / nCB;
    int co = cof * 16 + (lane & 15);
    int ci = (cb << 5) + (lane >> 4) * 8 + j;
    int wi = MT_WI[MODE][t];
    float v = src[((size_t)ci * Co + co) * 25 + (24 - wi)];
    unsigned uh = __float_as_uint(v) & 0xffff0000u;          // truncation hi
    float lo = v - __uint_as_float(uh);
    size_t base = (size_t)rest * 1024;                        // (t*nCB+cb)*nCoF+cof
    dst[base + lane * 8 + j] = (unsigned short)(uh >> 16);
    dst[base + 512 + lane * 8 + j] = bf16rne(lo);
}

// ---- MFMA conv: 16x16 pixel tile (input coords) x CO_F*16 out channels -----
// Block 256 thr = 4 waves; wave w owns output rows w*4..w*4+3; each lane:
// px = lane&15, co-group g = lane>>4. out(y*OS+soy, x*OS+sox).
template<int MODE, int CO_F>
__global__ __launch_bounds__(256) void conv_mfma(
    const float* __restrict__ in, const unsigned short* __restrict__ wpk,
    const float* __restrict__ bias, float* __restrict__ out,
    int Ci, int Co, int Hin, int Win, int Hout, int Wout,
    int nTX, int OS, int soy, int sox)
{
    constexpr int NT = MT_N[MODE];
    // s_x: [20 rows][20 cols] pixels, 144B each: 32ci hi (64B) | 32ci lo | pad
    __shared__ __align__(16) char s_x[400 * 144];
    const int tid = threadIdx.x;
    const int lane = tid & 63;
    const int wv = tid >> 6;
    const int px = lane & 15, g = lane >> 4;
    const int z = blockIdx.z;
    const int y0 = ((int)blockIdx.x / nTX) * 16;
    const int x0 = ((int)blockIdx.x % nTX) * 16;
    const int nCB = Ci >> 5;
    const int nCoF = Co >> 4;
    const int cof0 = (int)blockIdx.y * CO_F;
    const float* inz = in + (size_t)z * Ci * Hin * Win;

    f32x4 acc[4][CO_F];
#pragma unroll
    for (int rr = 0; rr < 4; ++rr)
#pragma unroll
        for (int cf = 0; cf < CO_F; ++cf) acc[rr][cf] = (f32x4){0.f, 0.f, 0.f, 0.f};

    for (int cb = 0; cb < nCB; ++cb) {
        // ---- stage 32 ci x 20x20 px with hi/lo split ----
        const float* inc = inz + ((size_t)cb << 5) * Hin * Win;
        for (int i = tid; i < 6400; i += 256) {
            int c2 = i / 400;                       // ci pair 0..15
            int rem = i - c2 * 400;
            int ry = rem / 20, rx = rem - ry * 20;
            int y = y0 + ry - 2, x = x0 + rx - 2;
            float v0 = 0.f, v1 = 0.f;
            if ((unsigned)y < (unsigned)Hin && (unsigned)x < (unsigned)Win) {
                const float* p = inc + ((size_t)(c2 * 2) * Hin + y) * Win + x;
                v0 = p[0];
                v1 = p[(size_t)Hin * Win];
            }
            unsigned u0 = __float_as_uint(v0) & 0xffff0000u;
            unsigned u1 = __float_as_uint(v1) & 0xffff0000u;
            unsigned short l0 = bf16rne(v0 - __uint_as_float(u0));
            unsigned short l1 = bf16rne(v1 - __uint_as_float(u1));
            char* base = &s_x[rem * 144 + c2 * 4];
            *(unsigned*)(base)      = (u0 >> 16) | (u1 & 0xffff0000u);
            *(unsigned*)(base + 64) = (unsigned)l0 | ((unsigned)l1 << 16);
        }
        __syncthreads();
        // ---- compute ----
#pragma unroll
        for (int t = 0; t < NT; ++t) {
            const int dy = MT_DY[MODE][t], dx = MT_DX[MODE][t];
            bfrag Bh[4], Bl[4];
#pragma unroll
            for (int rr = 0; rr < 4; ++rr) {
                int a = wv * 4 + rr;
                const char* p = &s_x[((a + dy + 2) * 20 + (dx + 2) + px) * 144 + g * 16];
                Bh[rr] = *(const bfrag*)p;
                Bl[rr] = *(const bfrag*)(p + 64);
            }
#pragma unroll
            for (int cf = 0; cf < CO_F; ++cf) {
                const unsigned short* wp =
                    wpk + ((size_t)(t * nCB + cb) * nCoF + (cof0 + cf)) * 1024 + (size_t)lane * 8;
                bfrag Ah = *(const bfrag*)wp;
                bfrag Al = *(const bfrag*)(wp + 512);
#pragma unroll
                for (int rr = 0; rr < 4; ++rr) {
                    acc[rr][cf] = __builtin_amdgcn_mfma_f32_16x16x32_bf16(Ah, Bh[rr], acc[rr][cf], 0, 0, 0);
                    acc[rr][cf] = __builtin_amdgcn_mfma_f32_16x16x32_bf16(Ah, Bl[rr], acc[rr][cf], 0, 0, 0);
                    acc[rr][cf] = __builtin_amdgcn_mfma_f32_16x16x32_bf16(Al, Bh[rr], acc[rr][cf], 0, 0, 0);
                }
            }
        }
        __syncthreads();
    }
    // ---- store: D layout col(px)=lane&15, row(co)= (lane>>4)*4 + reg ----
    const int ox = (x0 + px) * OS + sox;
    if (ox < Wout) {
#pragma unroll
        for (int rr = 0; rr < 4; ++rr) {
            int oy = (y0 + wv * 4 + rr) * OS + soy;
            if (oy < Hout) {
#pragma unroll
                for (int cf = 0; cf < CO_F; ++cf) {
                    int co = (cof0 + cf) * 16 + g * 4;
                    float* op = out + (((size_t)z * Co + co) * Hout + oy) * Wout + ox;
#pragma unroll
                    for (int i2 = 0; i2 < 4; ++i2) {
                        float v = acc[rr][cf][i2] + bias[co + i2];
                        op[(size_t)i2 * Hout * Wout] = v > 0.f ? v : 0.f;
                    }
                }
            }
        }
    }
}

// ---- stride-1 5x5 conv + bias + ReLU (fp32; encoder + t1b) ----------------
template<int CO_PER>
__global__ __launch_bounds__(256) void conv5x5_s1(
    const float* __restrict__ in, const float* __restrict__ w,   // w (Co,Ci,25)
    const float* __restrict__ bias, float* __restrict__ out,
    int Ci, int Co, int Hin, int Win, int Hout, int Wout, int nTX)
{
    __shared__ float s_in[2][36 * 36];
    const int z = blockIdx.z;
    const float* inz = in + (size_t)z * Ci * Hin * Win;
    float* outz = out + (size_t)z * Co * Hout * Wout;
    const int co0 = blockIdx.y * CO_PER;
    const int ty0 = ((int)blockIdx.x / nTX) * 32;
    const int tx0 = ((int)blockIdx.x % nTX) * 32;
    const int tid = threadIdx.x;
    const int r  = tid >> 3;
    const int c4 = (tid & 7) * 4;
    const int oy = ty0 + r;
    const int ox0 = tx0 + c4;
    const int iy0 = ty0 - 2, ix0 = tx0 - 2;

    float acc[CO_PER][4];
#pragma unroll
    for (int j = 0; j < CO_PER; ++j)
#pragma unroll
        for (int p = 0; p < 4; ++p) acc[j][p] = 0.f;

    for (int ci0 = 0; ci0 < Ci; ci0 += 2) {
        const int nci = (Ci - ci0 >= 2) ? 2 : 1;
        for (int s = 0; s < nci; ++s) {
            const float* inc = inz + (size_t)(ci0 + s) * Hin * Win;
            for (int i = tid; i < 36 * 36; i += 256) {
                int rr = i / 36, cc = i - rr * 36;
                int y = iy0 + rr, x = ix0 + cc;
                float v = 0.f;
                if (y >= 0 && y < Hin && x >= 0 && x < Win) v = inc[y * Win + x];
                s_in[s][i] = v;
            }
        }
        __syncthreads();
        for (int s = 0; s < nci; ++s) {
            const float* wc = w + (co0 * Ci + ci0 + s) * 25;
            float win[5][8];
#pragma unroll
            for (int ky = 0; ky < 5; ++ky) {
                const float* rowp = &s_in[s][(r + ky) * 36 + c4];
                float4 a = *(const float4*)rowp;
                float4 b = *(const float4*)(rowp + 4);
                win[ky][0]=a.x; win[ky][1]=a.y; win[ky][2]=a.z; win[ky][3]=a.w;
                win[ky][4]=b.x; win[ky][5]=b.y; win[ky][6]=b.z; win[ky][7]=b.w;
            }
#pragma unroll
            for (int j = 0; j < CO_PER; ++j) {
#pragma unroll
                for (int ky = 0; ky < 5; ++ky) {
#pragma unroll
                    for (int kx = 0; kx < 5; ++kx) {
                        float wv = wc[j * Ci * 25 + ky * 5 + kx];
#pragma unroll
                        for (int p = 0; p < 4; ++p)
                            acc[j][p] = fmaf(win[ky][p + kx], wv, acc[j][p]);
                    }
                }
            }
        }
        __syncthreads();
    }
    if (oy < Hout) {
#pragma unroll
        for (int j = 0; j < CO_PER; ++j) {
            const int co = co0 + j;
            const float bv = bias[co];
            float* orow = outz + (size_t)co * Hout * Wout + (size_t)oy * Wout;
#pragma unroll
            for (int p = 0; p < 4; ++p) {
                int ox = ox0 + p;
                if (ox < Wout) {
                    float v = acc[j][p] + bv;
                    orow[ox] = v > 0.f ? v : 0.f;
                }
            }
        }
    }
}

// ---- stride-2 5x5 conv + bias + ReLU (fp32; encoder) ----------------------
__global__ __launch_bounds__(256) void conv5x5_s2(
    const float* __restrict__ in, const float* __restrict__ w,
    const float* __restrict__ bias, float* __restrict__ out,
    int Ci, int Co, int Hin, int Win, int Hout, int Wout, int nTX)
{
    __shared__ float s_in[2][35 * 76];
    const int z = blockIdx.z;
    const float* inz = in + (size_t)z * Ci * Hin * Win;
    float* outz = out + (size_t)z * Co * Hout * Wout;
    const int tid = threadIdx.x;
    const int cq = tid & 7;
    const int r  = (tid >> 3) & 15;
    const int g  = tid >> 7;
    const int co0 = blockIdx.y * 16 + g * 8;
    const int ty0 = ((int)blockIdx.x / nTX) * 16;
    const int tx0 = ((int)blockIdx.x % nTX) * 32;
    const int oy = ty0 + r;
    const int ox0 = tx0 + cq * 4;
    const int iy0 = ty0 * 2, ix0 = tx0 * 2;

    float acc[8][4];
#pragma unroll
    for (int j = 0; j < 8; ++j)
#pragma unroll
        for (int p = 0; p < 4; ++p) acc[j][p] = 0.f;

    for (int ci0 = 0; ci0 < Ci; ci0 += 2) {
        const int nci = (Ci - ci0 >= 2) ? 2 : 1;
        for (int s = 0; s < nci; ++s) {
            const float* inc = inz + (size_t)(ci0 + s) * Hin * Win;
            for (int i = tid; i < 35 * 67; i += 256) {
                int rr = i / 67, cc = i - rr * 67;
                int y = iy0 + rr, x = ix0 + cc;
                float v = 0.f;
                if (y >= 0 && y < Hin && x >= 0 && x < Win) v = inc[y * Win + x];
                s_in[s][rr * 76 + cc] = v;
            }
        }
        __syncthreads();
        for (int s = 0; s < nci; ++s) {
            const float* wc = w + (co0 * Ci + ci0 + s) * 25;
            float win[5][12];
#pragma unroll
            for (int ky = 0; ky < 5; ++ky) {
                const float* rowp = &s_in[s][(2 * r + ky) * 76 + cq * 8];
                float4 a = *(const float4*)rowp;
                float4 b = *(const float4*)(rowp + 4);
                float4 c = *(const float4*)(rowp + 8);
                win[ky][0]=a.x; win[ky][1]=a.y; win[ky][2]=a.z;  win[ky][3]=a.w;
                win[ky][4]=b.x; win[ky][5]=b.y; win[ky][6]=b.z;  win[ky][7]=b.w;
                win[ky][8]=c.x; win[ky][9]=c.y; win[ky][10]=c.z; win[ky][11]=c.w;
            }
#pragma unroll
            for (int j = 0; j < 8; ++j) {
#pragma unroll
                for (int ky = 0; ky < 5; ++ky) {
#pragma unroll
                    for (int kx = 0; kx < 5; ++kx) {
                        float wv = wc[j * Ci * 25 + ky * 5 + kx];
#pragma unroll
                        for (int p = 0; p < 4; ++p)
                            acc[j][p] = fmaf(win[ky][2 * p + kx], wv, acc[j][p]);
                    }
                }
            }
        }
        __syncthreads();
    }
    if (oy < Hout) {
#pragma unroll
        for (int j = 0; j < 8; ++j) {
            const int co = co0 + j;
            const float bv = bias[co];
            float* orow = outz + (size_t)co * Hout * Wout + (size_t)oy * Wout;
#pragma unroll
            for (int p = 0; p < 4; ++p) {
                int ox = ox0 + p;
                if (ox < Wout) {
                    float v = acc[j][p] + bv;
                    orow[ox] = v > 0.f ? v : 0.f;
                }
            }
        }
    }
}

// ---- ConvTranspose2d stride=2 quad gather (fp32; t1a only) ----------------
template<int CO_PER>
__global__ __launch_bounds__(256) void convt5x5_quad(
    const float* __restrict__ in, const float* __restrict__ w,  // flipped (Co,Ci,25)
    const float* __restrict__ bias, float* __restrict__ out,
    int Ci, int Co, int Hin, int Win, int Hout, int Wout, int nTX)
{
    __shared__ float s_in[2][18 * 20];
    const int z = blockIdx.z;
    const float* inz = in + (size_t)z * Ci * Hin * Win;
    float* outz = out + (size_t)z * Co * Hout * Wout;
    const int co0 = blockIdx.y * CO_PER;
    const int a0 = ((int)blockIdx.x / nTX) * 16;
    const int b0 = ((int)blockIdx.x % nTX) * 16;
    const int tid = threadIdx.x;
    const int r = tid >> 4, c = tid & 15;

    float acc[CO_PER][4];
#pragma unroll
    for (int j = 0; j < CO_PER; ++j)
#pragma unroll
        for (int p = 0; p < 4; ++p) acc[j][p] = 0.f;

    for (int ci0 = 0; ci0 < Ci; ci0 += 2) {
        const int nci = (Ci - ci0 >= 2) ? 2 : 1;
        for (int s = 0; s < nci; ++s) {
            const float* inc = inz + (size_t)(ci0 + s) * Hin * Win;
            for (int i = tid; i < 18 * 18; i += 256) {
                int rr = i / 18, cc = i - rr * 18;
                int y = a0 - 2 + rr, x = b0 - 2 + cc;
                float v = 0.f;
                if (y >= 0 && y < Hin && x >= 0 && x < Win) v = inc[y * Win + x];
                s_in[s][rr * 20 + cc] = v;
            }
        }
        __syncthreads();
        for (int s = 0; s < nci; ++s) {
            const float* wc = w + (co0 * Ci + ci0 + s) * 25;
            float v[3][3];
#pragma unroll
            for (int i = 0; i < 3; ++i)
#pragma unroll
                for (int jx = 0; jx < 3; ++jx)
                    v[i][jx] = s_in[s][(r + i) * 20 + c + jx];
#pragma unroll
            for (int j = 0; j < CO_PER; ++j) {
                const float* wj = wc + j * Ci * 25;
#pragma unroll
                for (int ty = 0; ty < 3; ++ty)
#pragma unroll
                    for (int tx = 0; tx < 3; ++tx)
                        acc[j][0] = fmaf(v[ty][tx], wj[2*ty*5 + 2*tx], acc[j][0]);
#pragma unroll
                for (int ty = 0; ty < 3; ++ty)
#pragma unroll
                    for (int tx = 0; tx < 2; ++tx)
                        acc[j][1] = fmaf(v[ty][tx+1], wj[2*ty*5 + 2*tx+1], acc[j][1]);
#pragma unroll
                for (int ty = 0; ty < 2; ++ty)
#pragma unroll
                    for (int tx = 0; tx < 3; ++tx)
                        acc[j][2] = fmaf(v[ty+1][tx], wj[(2*ty+1)*5 + 2*tx], acc[j][2]);
#pragma unroll
                for (int ty = 0; ty < 2; ++ty)
#pragma unroll
                    for (int tx = 0; tx < 2; ++tx)
                        acc[j][3] = fmaf(v[ty+1][tx+1], wj[(2*ty+1)*5 + 2*tx+1], acc[j][3]);
            }
        }
        __syncthreads();
    }
    const int a = a0 + r, bq = b0 + c;
#pragma unroll
    for (int j = 0; j < CO_PER; ++j) {
        const int co = co0 + j;
        const float bv = bias[co];
        float* oc = outz + (size_t)co * Hout * Wout;
#pragma unroll
        for (int sy = 0; sy < 2; ++sy) {
            int oy = 2 * a + sy;
            if (oy < Hout) {
#pragma unroll
                for (int sx = 0; sx < 2; ++sx) {
                    int ox = 2 * bq + sx;
                    if (ox < Wout) {
                        float vv = acc[j][sy * 2 + sx] + bv;
                        oc[(size_t)oy * Wout + ox] = vv > 0.f ? vv : 0.f;
                    }
                }
            }
        }
    }
}

// Repack ConvTranspose weight (Ci,Co,5,5) -> (Co,Ci,25) with spatial flip.
__global__ __launch_bounds__(256) void repack_wt(
    const float* __restrict__ src, float* __restrict__ dst, int Ci, int Co)
{
    int n = Ci * Co * 25;
    int i = blockIdx.x * 256 + threadIdx.x;
    if (i >= n) return;
    int t = i % 25;
    int rest = i / 25;
    int ci = rest % Ci;
    int co = rest / Ci;
    dst[i] = src[((size_t)ci * Co + co) * 25 + (24 - t)];
}

// VQ: per position argmin_k( ||e_k||^2 - 2 z.e_k ); strict < == first-min.
__global__ __launch_bounds__(256) void vq_kernel(
    const float* __restrict__ before, const float* __restrict__ e,
    float* __restrict__ idxs_out, float* __restrict__ after,
    int npos, int HW)
{
    __shared__ float s_e[64 * 128];
    __shared__ float s_n[128];
    for (int i = threadIdx.x; i < 64 * 128; i += 256) s_e[i] = e[i];
    __syncthreads();
    if (threadIdx.x < 128) {
        int k = threadIdx.x;
        float s = 0.f;
#pragma unroll
        for (int d = 0; d < 64; ++d) { float v = s_e[d * 128 + k]; s += v * v; }
        s_n[k] = s;
    }
    __syncthreads();

    int p = blockIdx.x * 256 + threadIdx.x;
    if (p >= npos) return;
    int b = p / HW, r = p - b * HW;

    float zv[64];
#pragma unroll
    for (int d = 0; d < 64; ++d)
        zv[d] = before[((size_t)b * 64 + d) * HW + r];

    float best = 1e30f;
    int bi = 0;
    for (int k = 0; k < 128; ++k) {
        float dot = 0.f;
#pragma unroll
        for (int d = 0; d < 64; ++d) dot += zv[d] * s_e[d * 128 + k];
        float m = s_n[k] - 2.f * dot;
        if (m < best) { best = m; bi = k; }
    }
    idxs_out[p] = (float)bi;
#pragma unroll
    for (int d = 0; d < 64; ++d)
        after[((size_t)b * 64 + d) * HW + r] = s_e[d * 128 + bi];
}

extern "C" void kernel_launch(void* const* d_in, const int* in_sizes, int n_in,
                              void* d_out, int out_size, void* d_ws, size_t ws_size,
                              hipStream_t stream)
{
    const float* x     = (const float*)d_in[0];
    const float* e     = (const float*)d_in[1];
    const float* c1a_w = (const float*)d_in[2];  const float* c1a_b = (const float*)d_in[3];
    const float* c1b_w = (const float*)d_in[4];  const float* c1b_b = (const float*)d_in[5];
    const float* c2a_w = (const float*)d_in[6];  const float* c2a_b = (const float*)d_in[7];
    const float* c2b_w = (const float*)d_in[8];  const float* c2b_b = (const float*)d_in[9];
    const float* c3a_w = (const float*)d_in[10]; const float* c3a_b = (const float*)d_in[11];
    const float* c3b_w = (const float*)d_in[12]; const float* c3b_b = (const float*)d_in[13];
    const float* t3a_w = (const float*)d_in[14]; const float* t3a_b = (const float*)d_in[15];
    const float* t3b_w = (const float*)d_in[16]; const float* t3b_b = (const float*)d_in[17];
    const float* t2a_w = (const float*)d_in[18]; const float* t2a_b = (const float*)d_in[19];
    const float* t2b_w = (const float*)d_in[20]; const float* t2b_b = (const float*)d_in[21];
    const float* t1a_w = (const float*)d_in[22]; const float* t1a_b = (const float*)d_in[23];
    const float* t1b_w = (const float*)d_in[24]; const float* t1b_b = (const float*)d_in[25];

    float* out = (float*)d_out;
    float* ws  = (float*)d_ws;

    // d_out layout: recon | idxs | before | after
    float* o_recon  = out;                // 16*253*253 = 1,024,144
    float* o_idxs   = out + 1024144;     // 16*29*29   = 13,456
    float* o_before = out + 1037600;     // 16*64*29*29= 861,184
    float* o_after  = out + 1898784;     // 861,184

    // --- exact tensor sizes (floats) ---
    constexpr size_t S_H1F  = (size_t)16 * 64 * 256 * 256;   // 67,108,864
    constexpr size_t S_H1G  = (size_t)8  * 64 * 256 * 256;   // 33,554,432
    constexpr size_t S126x64  = (size_t)16 * 64  * 126 * 126; // 16,257,024
    constexpr size_t S126x128 = (size_t)16 * 128 * 126 * 126; // 32,514,048
    constexpr size_t S61x128  = (size_t)16 * 128 * 61 * 61;   // 7,620,608
    constexpr size_t S61x64   = (size_t)16 * 64  * 61 * 61;   // 3,810,304
    constexpr size_t S125x64  = (size_t)16 * 64  * 125 * 125; // 16,000,000
    constexpr size_t S253     = (size_t)16 * 253 * 253;       // 1,024,144
    constexpr size_t S_WF     = 923232;   // flipped t1a/t1b weights region
    constexpr size_t S_WPK    = 921600;   // MFMA packs: 1,843,200 ushorts

    // ---- full-batch plan ----
    constexpr size_t F_h1 = 0;
    constexpr size_t F_h2 = F_h1 + S_H1F;            // 67,108,864
    constexpr size_t F_h3 = 0;                       // aliases dead h1
    constexpr size_t F_h4 = F_h3 + S126x128;         // 32,514,048
    constexpr size_t F_h5 = F_h4 + S61x128;          // 40,134,656
    constexpr size_t F_wf = F_h5 + S61x64;           // 43,944,960
    constexpr size_t F_wk = F_wf + S_WF;             // 44,868,192
    constexpr size_t F_r1 = F_wk + S_WPK;            // 45,789,792
    constexpr size_t F_r2 = F_r1 + S61x128;          // 53,410,400
    constexpr size_t F_r3 = 0;                       // aliases dead h3/h4
    constexpr size_t F_r4 = F_r3 + S125x64;          // 16,000,000
    constexpr size_t F_r5 = F_r2 + S61x128;          // 61,031,008
    constexpr size_t FULL_NEED = F_h2 + S126x64;     // 83,365,888

    // ---- 8-image-group fallback plan ----
    constexpr size_t G_h1 = 0;
    constexpr size_t G_h2 = G_h1 + S_H1G;            // 33,554,432
    constexpr size_t G_h3 = 0;
    constexpr size_t G_h4 = G_h2;                    // overwrites dead h2
    constexpr size_t G_h5 = G_h4 + S61x128;          // 41,175,040
    constexpr size_t G_wf = G_h2 + S126x64;          // 49,811,456
    constexpr size_t G_wk = G_wf + S_WF;             // 50,734,688
    constexpr size_t G_r1 = 0;
    constexpr size_t G_r2 = G_r1 + S61x128;          // 7,620,608
    constexpr size_t G_r3 = G_r2 + S61x128;          // 15,241,216
    constexpr size_t G_r4 = G_r3 + S125x64;          // 31,241,216
    constexpr size_t G_r5 = G_r4 + S125x64;          // 47,241,216
    constexpr size_t G8_NEED = G_wk + S_WPK;         // 51,656,288

    static_assert(F_h5 + S61x64 <= F_wf, "h5/wf");
    static_assert(F_r5 + S253 <= F_h2, "r5 under h2");
    static_assert(G_r5 + S253 <= G_wf, "g8 r5/wf");
    static_assert(G_h5 + S61x64 <= G_wf, "g8 h5/wf");

    if (ws_size < G8_NEED * sizeof(float)) return;
    const bool full = ws_size >= FULL_NEED * sizeof(float);

    float *h1, *h2, *h3, *h4, *h5, *wf, *r1, *r2, *r3, *r4, *r5;
    unsigned short* wpkb;
    if (full) {
        h1 = ws + F_h1; h2 = ws + F_h2; h3 = ws + F_h3; h4 = ws + F_h4;
        h5 = ws + F_h5; wf = ws + F_wf; r1 = ws + F_r1; r2 = ws + F_r2;
        r3 = ws + F_r3; r4 = ws + F_r4; r5 = ws + F_r5;
        wpkb = (unsigned short*)(ws + F_wk);
    } else {
        h1 = ws + G_h1; h2 = ws + G_h2; h3 = ws + G_h3; h4 = ws + G_h4;
        h5 = ws + G_h5; wf = ws + G_wf; r1 = ws + G_r1; r2 = ws + G_r2;
        r3 = ws + G_r3; r4 = ws + G_r4; r5 = ws + G_r5;
        wpkb = (unsigned short*)(ws + G_wk);
    }
    float* wf_t1a = wf + 921600;     // 1*64*25 = 1,600
    float* wf_t1b = wf + 923200;     // 25
    // MFMA packs (ushort offsets)
    unsigned short* wpk_t3b = wpkb;                 // 819,200
    unsigned short* wpk_t2b = wpkb + 819200;        // 204,800
    unsigned short* wpk_t3a[4] = {wpkb + 1024000, wpkb + 1171456, wpkb + 1269760, wpkb + 1368064};
    unsigned short* wpk_t2a[4] = {wpkb + 1433600, wpkb + 1581056, wpkb + 1679360, wpkb + 1777664};

    // --- weight prep (dead-scratch regions; ordered before decoder use) ---
    repack_wt<<<dim3((64 * 25 + 255) / 256), 256, 0, stream>>>(t1a_w, wf_t1a, 64, 1);
    repack_wt<<<dim3(1), 256, 0, stream>>>(t1b_w, wf_t1b, 1, 1);
    pack_w_mfma<0><<<dim3(1600), 256, 0, stream>>>(t3b_w, wpk_t3b, 128, 128);
    pack_w_mfma<0><<<dim3(400), 256, 0, stream>>>(t2b_w, wpk_t2b, 64, 64);
    pack_w_mfma<1><<<dim3(288), 256, 0, stream>>>(t3a_w, wpk_t3a[0], 64, 128);
    pack_w_mfma<2><<<dim3(192), 256, 0, stream>>>(t3a_w, wpk_t3a[1], 64, 128);
    pack_w_mfma<3><<<dim3(192), 256, 0, stream>>>(t3a_w, wpk_t3a[2], 64, 128);
    pack_w_mfma<4><<<dim3(128), 256, 0, stream>>>(t3a_w, wpk_t3a[3], 64, 128);
    pack_w_mfma<1><<<dim3(288), 256, 0, stream>>>(t2a_w, wpk_t2a[0], 128, 64);
    pack_w_mfma<2><<<dim3(192), 256, 0, stream>>>(t2a_w, wpk_t2a[1], 128, 64);
    pack_w_mfma<3><<<dim3(192), 256, 0, stream>>>(t2a_w, wpk_t2a[2], 128, 64);
    pack_w_mfma<4><<<dim3(128), 256, 0, stream>>>(t2a_w, wpk_t2a[3], 128, 64);

    // --- encoder (fp32, unchanged) ---
    if (full) {
        conv5x5_s1<8><<<dim3(64, 8, 16), 256, 0, stream>>>(
            x, c1a_w, c1a_b, h1, 1, 64, 256, 256, 256, 256, 8);
        conv5x5_s2<<<dim3(32, 4, 16), 256, 0, stream>>>(
            h1, c1b_w, c1b_b, h2, 64, 64, 256, 256, 126, 126, 4);
    } else {
        for (int g = 0; g < 2; ++g) {
            conv5x5_s1<8><<<dim3(64, 8, 8), 256, 0, stream>>>(
                x + (size_t)g * 8 * 65536, c1a_w, c1a_b, h1,
                1, 64, 256, 256, 256, 256, 8);
            conv5x5_s2<<<dim3(32, 4, 8), 256, 0, stream>>>(
                h1, c1b_w, c1b_b, h2 + (size_t)g * 8 * 64 * 126 * 126,
                64, 64, 256, 256, 126, 126, 4);
        }
    }
    conv5x5_s1<8><<<dim3(16, 16, 16), 256, 0, stream>>>(
        h2, c2a_w, c2a_b, h3, 64, 128, 126, 126, 126, 126, 4);
    conv5x5_s2<<<dim3(8, 8, 16), 256, 0, stream>>>(
        h3, c2b_w, c2b_b, h4, 128, 128, 126, 126, 61, 61, 2);
    conv5x5_s1<8><<<dim3(4, 8, 16), 256, 0, stream>>>(
        h4, c3a_w, c3a_b, h5, 128, 64, 61, 61, 61, 61, 2);
    conv5x5_s2<<<dim3(2, 4, 16), 256, 0, stream>>>(
        h5, c3b_w, c3b_b, o_before, 64, 64, 61, 61, 29, 29, 1);

    // --- VQ ---
    vq_kernel<<<dim3(53), 256, 0, stream>>>(o_before, e, o_idxs, o_after, 13456, 841);

    // --- decoder: MFMA for t3a/t3b/t2a/t2b; fp32 for t1a/t1b ---
    // t3a: 64->128, 29->61 (4 parities)
    conv_mfma<1, 4><<<dim3(4, 2, 16), 256, 0, stream>>>(
        o_after, wpk_t3a[0], t3a_b, r1, 64, 128, 29, 29, 61, 61, 2, 2, 0, 0);
    conv_mfma<2, 4><<<dim3(4, 2, 16), 256, 0, stream>>>(
        o_after, wpk_t3a[1], t3a_b, r1, 64, 128, 29, 29, 61, 61, 2, 2, 0, 1);
    conv_mfma<3, 4><<<dim3(4, 2, 16), 256, 0, stream>>>(
        o_after, wpk_t3a[2], t3a_b, r1, 64, 128, 29, 29, 61, 61, 2, 2, 1, 0);
    conv_mfma<4, 4><<<dim3(4, 2, 16), 256, 0, stream>>>(
        o_after, wpk_t3a[3], t3a_b, r1, 64, 128, 29, 29, 61, 61, 2, 2, 1, 1);
    // t3b: 128->128 @61 s1 conv
    conv_mfma<0, 4><<<dim3(16, 2, 16), 256, 0, stream>>>(
        r1, wpk_t3b, t3b_b, r2, 128, 128, 61, 61, 61, 61, 4, 1, 0, 0);
    // t2a: 128->64, 61->125 (4 parities)
    conv_mfma<1, 4><<<dim3(16, 1, 16), 256, 0, stream>>>(
        r2, wpk_t2a[0], t2a_b, r3, 128, 64, 61, 61, 125, 125, 4, 2, 0, 0);
    conv_mfma<2, 4><<<dim3(16, 1, 16), 256, 0, stream>>>(
        r2, wpk_t2a[1], t2a_b, r3, 128, 64, 61, 61, 125, 125, 4, 2, 0, 1);
    conv_mfma<3, 4><<<dim3(16, 1, 16), 256, 0, stream>>>(
        r2, wpk_t2a[2], t2a_b, r3, 128, 64, 61, 61, 125, 125, 4, 2, 1, 0);
    conv_mfma<4, 4><<<dim3(16, 1, 16), 256, 0, stream>>>(
        r2, wpk_t2a[3], t2a_b, r3, 128, 64, 61, 61, 125, 125, 4, 2, 1, 1);
    // t2b: 64->64 @125 s1 conv
    conv_mfma<0, 4><<<dim3(64, 1, 16), 256, 0, stream>>>(
        r3, wpk_t2b, t2b_b, r4, 64, 64, 125, 125, 125, 125, 8, 1, 0, 0);
    // t1a/t1b (fp32)
    convt5x5_quad<1><<<dim3(64, 1, 16), 256, 0, stream>>>(
        r4, wf_t1a, t1a_b, r5, 64, 1, 125, 125, 253, 253, 8);
    conv5x5_s1<1><<<dim3(64, 1, 16), 256, 0, stream>>>(
        r5, wf_t1b, t1b_b, o_recon, 1, 1, 253, 253, 253, 253, 8);
}